// Round 3
// baseline (186.937 us; speedup 1.0000x reference)
//
#include <hip/hip_runtime.h>

// JointBilateralFilter B=16,C=1,H=768,W=1024 fp32, 9x9, sigma_s=2, sigma_r=0.1.
// valid = (sparse != 1.0); constant pad 1.0 => out-of-image taps never contribute.
// ~5% valid density. Gather-scan: wave tile 16x8 px, 2 px/lane (gx, gx+8), all
// per-entry math 2-wide packed fp32. LDS table folds box test via -1e30 sentinel.
//
// R9 post-mortem: TS=48 vs 68 both 2-way-per-half => SQ_LDS_BANK_CONFLICT ~7.6M
// is FREE aliasing (m136), not a stall. Keep TS=68.
//
// R10 (this round): LOADS-FIRST reorder of the A/B entry pair. Old structure
// A{decode,ds_read2,math} -> if(m) B{...} meant B's ds_read2 couldn't issue
// until A's math retired (program order across the uniform branch) => ~60cy DS
// latency exposed per entry with only ~12cy cover. New order: decode A, issue
// ds_read2 A, decode B, issue ds_read2 B, 4x readlane, math A, math B. Both
// reads hide under ~26cy of math + TLP.

#define HH 768
#define WW 1024
#define BB 16
#define CS (-0.18033688011112042f)   /* -log2(e)/8  */
#define CR (-72.13475204444817f)     /* -50*log2(e) */

#define TS 68                        /* table row stride: 2-way-per-half banks (free) */
#define TROWS 31                     /* dy in [-15,15] */
#define TSIZE (TROWS * TS)           /* 2108 floats = 8432 B */
#define TF4   (TSIZE / 4)            /* 527 float4 */

typedef float f2 __attribute__((ext_vector_type(2)));

__device__ __forceinline__ int rfl(int x) { return __builtin_amdgcn_readfirstlane(x); }
__device__ __forceinline__ float rlanef(float v, int b) {
    return __int_as_float(__builtin_amdgcn_readlane(__float_as_int(v), b));
}
__device__ __forceinline__ f2 splat(float x) { f2 r; r.x = x; r.y = x; return r; }

__global__ __launch_bounds__(256) void jbf_kernel(
    const float* __restrict__ sparse,
    const float* __restrict__ depth,
    float* __restrict__ out)
{
    __shared__ __align__(16) float Tab[TSIZE];
    const int tid  = (int)threadIdx.x;
    const int lane = tid & 63;
    const int wv   = tid >> 6;                    // 4 waves/block, 2x2 tiles

    // ---- table build: float4 fill -1e30, barrier, write the 81 in-box cells ----
    {
        float4 s; s.x = -1e30f; s.y = -1e30f; s.z = -1e30f; s.w = -1e30f;
        float4* t4 = (float4*)Tab;
        #pragma unroll
        for (int i = 0; i < 3; ++i) {
            const int idx = tid + 256 * i;
            if (idx < TF4) t4[idx] = s;
        }
    }
    __syncthreads();
    if (tid < 81) {
        const int rr = (tid * 57) >> 9;           // tid/9 for tid<81
        const int cc = tid - 9 * rr;
        const float dy = (float)(rr - 4), dx = (float)(cc - 4);
        Tab[(rr + 11) * TS + cc + 19] = CS * fmaf(dy, dy, dx * dx);
    }
    __syncthreads();

    // ---- wave-uniform tile constants (SGPRs) ----
    const int tx = rfl(((int)blockIdx.x << 5) + ((wv & 1) << 4));   // 16-wide tile
    const int ty = rfl(((int)blockIdx.y << 4) + ((wv >> 1) << 3));  // 8-tall tile
    const int px0 = rfl(min(max(tx - 4, 0), WW - 24));              // 24-col window
    const int py0 = rfl(min(max(ty - 4, 0), HH - 16));              // 16-row window
    const int txoff = tx - px0;                   // 0..8
    const int tyoff = ty - py0;                   // 0..8

    const size_t plane = (size_t)blockIdx.z * (size_t)(HH * WW);
    const float* sp = sparse + plane;
    const float* dp = depth  + plane;

    // ---- stage 16x24 window: 3 float2 per lane per input ----
    const int r  = lane >> 2;                     // 0..15 window row
    const int c0 = (lane & 3) << 1;               // float2 col 0,2,4,6 (+8 per j)
    const float* wbs = sp + (py0 + r) * WW + px0 + c0;
    const float* wbd = dp + (py0 + r) * WW + px0 + c0;
    const f2 s20 = *(const f2*)(wbs);
    const f2 s21 = *(const f2*)(wbs + 8);
    const f2 s22 = *(const f2*)(wbs + 16);
    const f2 d20 = *(const f2*)(wbd);
    const f2 d21 = *(const f2*)(wbd + 8);
    const f2 d22 = *(const f2*)(wbd + 16);

    // ---- per-lane pixel pair (gx, gx+8) ----
    const int my = lane >> 3, mx = lane & 7;
    const int gy = ty + my, gx = tx + mx;
    const float myd0 = dp[gy * WW + gx];
    const float myd1 = dp[gy * WW + gx + 8];
    f2 nmyd; nmyd.x = -myd0; nmyd.y = -myd1;
    const int clane_w = my * TS + mx;             // per-lane table float offset

    f2 numA = splat(0.0f), denA = splat(0.0f);
    f2 numB = splat(0.0f), denB = splat(0.0f);
    const f2 crp = splat(CR);

    // SALU base: TS*(dy+15) + (dx0+23) - 8 decomposition (lane part = clane_w)
    const int sbase0 = TS * (15 - tyoff) + (23 - txoff) - 8;

    #pragma unroll
    for (int j = 0; j < 3; ++j) {
        const f2 s2 = (j == 0) ? s20 : (j == 1) ? s21 : s22;
        const f2 d2 = (j == 0) ? d20 : (j == 1) ? d21 : d22;
        #pragma unroll
        for (int k = 0; k < 2; ++k) {
            const float svk = k ? s2.y : s2.x;
            const float dvk = k ? d2.y : d2.x;
            const int sbase = sbase0 + 8 * j + k;          // SALU
            unsigned long long m = __ballot(svk != 1.0f);
            while (m) {                                     // uniform scalar loop
                // ---- decode + issue LOADS for both entries first ----
                const int b0 = (int)__builtin_ctzll(m);
                m &= (m - 1ull);
                const int SW0 = sbase + (b0 >> 2) * TS + ((b0 & 3) << 1); // SALU
                const float* tb0 = Tab + (SW0 - clane_w);   // one v_add
                f2 tp0; tp0.x = tb0[8]; tp0.y = tb0[0];     // ds_read2_b32 (early)

                const bool hasB = (m != 0ull);
                int b1 = b0;
                if (hasB) { b1 = (int)__builtin_ctzll(m); m &= (m - 1ull); }
                const int SW1 = sbase + (b1 >> 2) * TS + ((b1 & 3) << 1);
                const float* tb1 = Tab + (SW1 - clane_w);
                f2 tp1; tp1.x = tb1[8]; tp1.y = tb1[0];     // ds_read2_b32 (early)

                const float sv0 = rlanef(svk, b0);
                const float dv0 = rlanef(dvk, b0);
                const float sv1 = rlanef(svk, b1);
                const float dv1 = rlanef(dvk, b1);

                // ---- math A ----
                {
                    const f2 diff = nmyd + splat(dv0);
                    const f2 q = diff * crp;
                    const f2 arg = q * diff + tp0;          // pk_fma
                    f2 w; w.x = __builtin_amdgcn_exp2f(arg.x);
                    w.y = __builtin_amdgcn_exp2f(arg.y);
                    denA += w;
                    numA += w * splat(sv0);                 // pk_fma
                }
                // ---- math B (dup entry suppressed by guard) ----
                if (hasB) {
                    const f2 diff = nmyd + splat(dv1);
                    const f2 q = diff * crp;
                    const f2 arg = q * diff + tp1;
                    f2 w; w.x = __builtin_amdgcn_exp2f(arg.x);
                    w.y = __builtin_amdgcn_exp2f(arg.y);
                    denB += w;
                    numB += w * splat(sv1);
                }
            }
        }
    }

    const float n0 = numA.x + numB.x, n1 = numA.y + numB.y;
    const float e0 = denA.x + denB.x, e1 = denA.y + denB.y;
    float r0 = n0 * __builtin_amdgcn_rcpf(e0 + 1e-8f);
    r0 = (e0 < 1e-8f) ? 1.0f : r0;
    float r1 = n1 * __builtin_amdgcn_rcpf(e1 + 1e-8f);
    r1 = (e1 < 1e-8f) ? 1.0f : r1;
    float* op = out + plane + (size_t)gy * WW + gx;
    op[0] = r0;
    op[8] = r1;
}

extern "C" void kernel_launch(void* const* d_in, const int* in_sizes, int n_in,
                              void* d_out, int out_size, void* d_ws, size_t ws_size,
                              hipStream_t stream)
{
    const float* sparse = (const float*)d_in[0];
    const float* depth  = (const float*)d_in[1];
    float* out = (float*)d_out;
    dim3 grid(WW / 32, HH / 16, BB);   // 32 x 48 x 16 blocks, 4 waves each
    jbf_kernel<<<grid, dim3(256, 1, 1), 0, stream>>>(sparse, depth, out);
}